// Round 5
// baseline (4347.456 us; speedup 1.0000x reference)
//
#include <hip/hip_runtime.h>
#include <hip/hip_fp16.h>
#include <math.h>

#define BB 128
#define TT 512
#define DD 256
#define HH 256
#define NG 1024  // 4*H

typedef _Float16 h2_t __attribute__((ext_vector_type(2)));
typedef _Float16 f16x8 __attribute__((ext_vector_type(8)));
typedef float f32x4 __attribute__((ext_vector_type(4)));
typedef unsigned int u32x4 __attribute__((ext_vector_type(4)));

#if __has_builtin(__builtin_amdgcn_fdot2)
__device__ __forceinline__ float fdot2_(h2_t a, h2_t b, float c) {
    return __builtin_amdgcn_fdot2(a, b, c, false);
}
#else
__device__ __forceinline__ float fdot2_(h2_t a, h2_t b, float c) {
    return c + (float)a.x * (float)b.x + (float)a.y * (float)b.y;
}
#endif

__device__ __forceinline__ float sigmoidf_(float x) {
    return 1.0f / (1.0f + __expf(-x));
}
__device__ __forceinline__ float tanhf_(float x) {
    x = fminf(15.0f, fmaxf(-15.0f, x));
    float e = __expf(2.0f * x);
    return (e - 1.0f) / (e + 1.0f);
}
__device__ __forceinline__ void dot4_(float4& acc, uint4 u, h2_t h) {
    acc.x = fdot2_(__builtin_bit_cast(h2_t, u.x), h, acc.x);
    acc.y = fdot2_(__builtin_bit_cast(h2_t, u.y), h, acc.y);
    acc.z = fdot2_(__builtin_bit_cast(h2_t, u.z), h, acc.z);
    acc.w = fdot2_(__builtin_bit_cast(h2_t, u.w), h, acc.w);
}

// MFMA with B operand pinned in AGPRs (direct consume, no accvgpr_read chain).
__device__ __forceinline__ void mfma_a_(f32x4& d, f16x8 a, u32x4 b) {
    asm("v_mfma_f32_16x16x32_f16 %0, %1, %2, %0" : "+v"(d) : "v"(a), "a"(b));
}

// Pack (one pass):
//  Wg16  [n][k] fp16 RAW W_ih rows (gate-major n = g)       -> GEMM B operand
//  Wh16g [n][k] fp16 RAW W_hh rows                          -> rec B operand
//  bias_r[n] = b_ih[n] + b_hh[n]  (raw order)               -> GEMM epilogue
//  Wi16/Wh16 fp16 k-pair-major packed (n_p = j*4+q) + bias_p -> fallback only
__global__ void pack2(const float* __restrict__ W_ih, const float* __restrict__ W_hh,
                      const float* __restrict__ b_ih, const float* __restrict__ b_hh,
                      __half* __restrict__ Wg16, __half* __restrict__ Wh16g,
                      __half* __restrict__ Wi16, __half* __restrict__ Wh16,
                      float* __restrict__ bias_p, float* __restrict__ bias_r) {
    int idx = blockIdx.x * 256 + threadIdx.x;   // 0..262143
    int n = idx >> 8;
    int k = idx & 255;
    float wih = W_ih[n * 256 + k];
    float whh = W_hh[n * 256 + k];
    Wg16[n * 256 + k]  = __float2half(wih);
    Wh16g[n * 256 + k] = __float2half(whh);
    int np = (n & 255) * 4 + (n >> 8);          // packed col with g(np) = n
    size_t hidx = ((size_t)(k >> 1) * 1024 + np) * 2 + (k & 1);
    Wi16[hidx] = __float2half(wih);
    Wh16[hidx] = __float2half(whh);
    if (idx < 1024) {
        bias_r[idx] = b_ih[idx] + b_hh[idx];
        int gg = (idx & 3) * 256 + (idx >> 2);
        bias_p[idx] = b_ih[gg] + b_hh[gg];
    }
}

// x fp32 -> fp16, 8 elements/thread
__global__ __launch_bounds__(256) void cvt_x(const float* __restrict__ X,
                                             __half* __restrict__ X16) {
    size_t i = ((size_t)blockIdx.x * 256 + threadIdx.x) * 8;
    float4 a = *(const float4*)&X[i];
    float4 b = *(const float4*)&X[i + 4];
    f16x8 v;
    v[0] = (_Float16)a.x; v[1] = (_Float16)a.y; v[2] = (_Float16)a.z; v[3] = (_Float16)a.w;
    v[4] = (_Float16)b.x; v[5] = (_Float16)b.y; v[6] = (_Float16)b.z; v[7] = (_Float16)b.w;
    *(f16x8*)&X16[i] = v;
}

// xg chunk GEMM via MFMA f16. m-index = t_loc*128 + s (t-major!): each 64-row
// m-block = 64 samples at ONE t. Epilogue writes xg_p in the rec's packed
// layout: halfs at ((((t_loc*8 + blk)*8 + w)*2 + jt)*4 + q)*256 + j15*16 + m16
// where n = q*256 + w*32 + jt*16 + j15 (gate-major), s = blk*16 + m16.
__global__ __launch_bounds__(256) void xg_gemm2(const __half* __restrict__ X16,
                                                const __half* __restrict__ Wg16,
                                                const float* __restrict__ bias_r,
                                                __half* __restrict__ xg_p,
                                                int t0) {
    __shared__ __align__(16) __half st[64][80];   // [n_loc][m_loc], pitch 160 B
    int tid = threadIdx.x;
    int w = tid >> 6, lane = tid & 63;
    int row16 = lane & 15, quad = lane >> 4;
    int t_loc = blockIdx.x >> 1;
    int s0 = (blockIdx.x & 1) * 64;
    int n0 = blockIdx.y * 64;

    int s = s0 + w * 16 + row16;
    const __half* aptr = X16 + ((size_t)s * 512 + t0 + t_loc) * 256 + quad * 8;
    f16x8 afrag[8];
#pragma unroll
    for (int kk = 0; kk < 8; ++kk)
        afrag[kk] = *(const f16x8*)(aptr + kk * 32);

#pragma unroll
    for (int cg = 0; cg < 4; ++cg) {
        int n = n0 + cg * 16 + row16;
        const __half* bptr = Wg16 + (size_t)n * 256 + quad * 8;
        f32x4 acc = {0.0f, 0.0f, 0.0f, 0.0f};
#pragma unroll
        for (int kk = 0; kk < 8; ++kk) {
            f16x8 bfrag = *(const f16x8*)(bptr + kk * 32);
            acc = __builtin_amdgcn_mfma_f32_16x16x32_f16(afrag[kk], bfrag, acc, 0, 0, 0);
        }
        float bias = bias_r[n];
#pragma unroll
        for (int r = 0; r < 4; ++r)
            st[cg * 16 + row16][w * 16 + quad * 4 + r] = __float2half(acc[r] + bias);
    }
    __syncthreads();
    // readout: one 32 B chunk (16 halfs, m16 = 0..15) per thread, coalesced
    int j15 = tid & 15;
    int jt  = (tid >> 4) & 1;
    int wq  = (tid >> 5) & 1;
    int blkq = tid >> 6;
    int n_loc = ((tid >> 4) & 3) * 16 + j15;      // wq*32 + jt*16 + j15
    const uint4* src = (const uint4*)&st[n_loc][blkq * 16];
    uint4 v0 = src[0], v1 = src[1];
    int q  = n0 >> 8;
    int wp = ((n0 & 255) >> 5) + wq;
    int blk = (s0 >> 4) + blkq;
    size_t off = (((((size_t)t_loc * 8 + blk) * 8 + wp) * 2 + jt) * 4 + q) * 256
                 + (size_t)j15 * 16;
    *(uint4*)&xg_p[off] = v0;
    *(uint4*)&xg_p[off + 8] = v1;
}

// Recurrence v6 (MFMA, schedule-fixed): 8 blocks x 512 threads (8 waves,
// 2 waves/SIMD -> 256 reg budget: 128 AGPR weights + <=~120 arch VGPR).
//
// R4 failed on register pressure (VGPR_Count pegged at 128; ~190 live ->
// per-step scratch spills) and zero latency cover for the 2nd stream batch.
// v6 keeps the verified math/layouts and fixes ONLY the schedule:
//   - windowed streaming: svA (kt6,nt1..7) issued at step top, consumed
//     after the VMEM-free AGPR section; svB (kt7,*) issued right after,
//     covered by the interposed LDS kt4,5 section. Never both held long.
//   - kt accumulation order 0,1,2,3,6,4,5,7 (sum is commutative).
//   - uniform weight/xg bases via readfirstlane(w) -> saddr addressing
//     (no 15 held 64-bit VGPR address pairs).
// Peak live ~110 VGPR.
__global__ __launch_bounds__(512, 2) void lstm_mfma16(const __half* __restrict__ xg_p,
                                                      const __half* __restrict__ Wh16g,
                                                      const int* __restrict__ x_len,
                                                      float* __restrict__ out,
                                                      __half* __restrict__ h_state,
                                                      float* __restrict__ c_state,
                                                      int t0, int Tc) {
    __shared__ __align__(16) __half wlds[8][17][64][8];   // 139264 B
    __shared__ __align__(16) char hsraw[2 * 8192];        // 16 KB (2 x 16x256 f16)
    int tid = threadIdx.x;
    int w = tid >> 6, lane = tid & 63;
    int wu = __builtin_amdgcn_readfirstlane(w);           // wave-uniform w
    int l15 = lane & 15, k2 = lane >> 4;   // frag coords
    int mq = k2;                            // acc coords: lane = mq*16 + j15
    int blk = blockIdx.x;                   // 0..7

    // element offset (halfs): row (nt>>1)*256 + wu*32 + (nt&1)*16  [uniform]
    //                        + l15*256 + kt*32 + k2*8               [lane]
#define WBASE(nt) ((size_t)(((nt) >> 1) * 256 + wu * 32 + ((nt) & 1) * 16) * 256)
#define LDW(kt, nt) (*(const uint4*)(Wh16g + WBASE(nt) + (size_t)l15 * 256 + (kt) * 32 + k2 * 8))

    // ---- LDS weight fill: wave w's 17 tiles (kt 4,5 x nt 0..7; kt6 nt0)
#pragma unroll
    for (int tI = 0; tI < 17; ++tI) {
        int kt = (tI < 16) ? (4 + (tI >> 3)) : 6;
        int nt = (tI < 16) ? (tI & 7) : 0;
        uint4 v = LDW(kt, nt);
        *(uint4*)&wlds[wu][tI][lane][0] = v;
    }
    // ---- AGPR tiles: kt 0..3 x nt 0..7
    u32x4 wa[32];
#pragma unroll
    for (int kt = 0; kt < 4; ++kt)
#pragma unroll
        for (int nt = 0; nt < 8; ++nt) {
            uint4 v = LDW(kt, nt);
            u32x4 t = {v.x, v.y, v.z, v.w};
            asm volatile("" : "+a"(t));   // pin: contiguous AGPR quad, no remat
            wa[kt * 8 + nt] = t;
        }

    // ---- per-lane state
    int jbase = wu * 32 + l15;             // + jt*16
    int sbase = blk * 16 + mq * 4;         // + r
    float creg[2][4];
    int len[4];
#pragma unroll
    for (int r = 0; r < 4; ++r) len[r] = x_len[sbase + r];
#pragma unroll
    for (int jt = 0; jt < 2; ++jt)
#pragma unroll
        for (int r = 0; r < 4; ++r)
            creg[jt][r] = (t0 == 0) ? 0.0f
                        : c_state[(size_t)(sbase + r) * 256 + jbase + jt * 16];

    // ---- hs[0] init (swizzled): thread (m = tid>>5, kg = tid&31)
    {
        int m = tid >> 5, kg = tid & 31;
        uint4 hv = {0u, 0u, 0u, 0u};
        if (t0 != 0)
            hv = *(const uint4*)(h_state + (size_t)(blk * 16 + m) * 256 + kg * 8);
        *(uint4*)(hsraw + m * 512 + ((kg * 16) ^ ((m & 7) << 4))) = hv;
    }
    __syncthreads();

    int swz = (l15 & 7) << 4;
    const __half* xg_base = xg_p + ((size_t)blk * 8 + wu) * 2048 + l15 * 16 + mq * 4;

    for (int tt = 0; tt < Tc; ++tt) {
        const char* hsc = hsraw + ((tt & 1) << 13);
        char* hsn = hsraw + (((tt & 1) ^ 1) << 13);

        // xg loads (consumed at gates, near end of step -> full-step cover)
        const __half* xgt = xg_base + (size_t)tt * 131072;   // tt*8*8*2048
        uint2 xv[2][4];
#pragma unroll
        for (int jt = 0; jt < 2; ++jt)
#pragma unroll
            for (int q = 0; q < 4; ++q)
                xv[jt][q] = *(const uint2*)(xgt + (jt * 4 + q) * 256);

        // stream window A: kt6, nt1..7 (consumed after the AGPR section)
        uint4 svA[7];
#pragma unroll
        for (int nt = 1; nt < 8; ++nt) svA[nt - 1] = LDW(6, nt);

        f32x4 acc[8];
#pragma unroll
        for (int nt = 0; nt < 8; ++nt) acc[nt] = (f32x4){0.f, 0.f, 0.f, 0.f};

        // kt 0..3: AGPR tiles (no VMEM dependence -> covers svA latency)
#pragma unroll
        for (int kt = 0; kt < 4; ++kt) {
            uint4 hv = *(const uint4*)(hsc + l15 * 512 + ((kt * 64 + k2 * 16) ^ swz));
            f16x8 af = __builtin_bit_cast(f16x8, hv);
#pragma unroll
            for (int nt = 0; nt < 8; ++nt) mfma_a_(acc[nt], af, wa[kt * 8 + nt]);
        }
        // kt 6: nt0 LDS, nt1..7 = svA
        {
            uint4 hv = *(const uint4*)(hsc + l15 * 512 + ((6 * 64 + k2 * 16) ^ swz));
            f16x8 af = __builtin_bit_cast(f16x8, hv);
            f16x8 b0 = *(const f16x8*)&wlds[wu][16][lane][0];
            acc[0] = __builtin_amdgcn_mfma_f32_16x16x32_f16(af, b0, acc[0], 0, 0, 0);
#pragma unroll
            for (int nt = 1; nt < 8; ++nt)
                acc[nt] = __builtin_amdgcn_mfma_f32_16x16x32_f16(
                    af, __builtin_bit_cast(f16x8, svA[nt - 1]), acc[nt], 0, 0, 0);
        }
        // stream window B: kt7 (svA regs dead; covered by LDS kt4,5 below)
        uint4 svB[8];
#pragma unroll
        for (int nt = 0; nt < 8; ++nt) svB[nt] = LDW(7, nt);

        // kt 4,5: LDS tiles (covers svB latency)
#pragma unroll
        for (int kt = 4; kt < 6; ++kt) {
            uint4 hv = *(const uint4*)(hsc + l15 * 512 + ((kt * 64 + k2 * 16) ^ swz));
            f16x8 af = __builtin_bit_cast(f16x8, hv);
#pragma unroll
            for (int nt = 0; nt < 8; ++nt) {
                f16x8 bf = *(const f16x8*)&wlds[wu][(kt - 4) * 8 + nt][lane][0];
                acc[nt] = __builtin_amdgcn_mfma_f32_16x16x32_f16(af, bf, acc[nt], 0, 0, 0);
            }
        }
        // kt 7: svB
        {
            uint4 hv = *(const uint4*)(hsc + l15 * 512 + ((7 * 64 + k2 * 16) ^ swz));
            f16x8 af = __builtin_bit_cast(f16x8, hv);
#pragma unroll
            for (int nt = 0; nt < 8; ++nt)
                acc[nt] = __builtin_amdgcn_mfma_f32_16x16x32_f16(
                    af, __builtin_bit_cast(f16x8, svB[nt]), acc[nt], 0, 0, 0);
        }

        // gates: all in-lane (nt = q*2 + jt), 8 (j,m) pairs per lane
        int t = t0 + tt;
#pragma unroll
        for (int jt = 0; jt < 2; ++jt) {
            const _Float16* xi = (const _Float16*)&xv[jt][0];
            const _Float16* xf = (const _Float16*)&xv[jt][1];
            const _Float16* xg_ = (const _Float16*)&xv[jt][2];
            const _Float16* xo = (const _Float16*)&xv[jt][3];
            int jj = jbase + jt * 16;
#pragma unroll
            for (int r = 0; r < 4; ++r) {
                float gi = acc[0 + jt][r] + (float)xi[r];
                float gf = acc[2 + jt][r] + (float)xf[r];
                float gg = acc[4 + jt][r] + (float)xg_[r];
                float go = acc[6 + jt][r] + (float)xo[r];
                float iv = sigmoidf_(gi), fv = sigmoidf_(gf);
                float gv = tanhf_(gg),   ov = sigmoidf_(go);
                float c = fv * creg[jt][r] + iv * gv;
                creg[jt][r] = c;
                float h = ov * tanhf_(c);
                out[((size_t)(sbase + r) * 512 + t) * 256 + jj] =
                    (t < len[r]) ? h : 0.0f;
                int m16 = mq * 4 + r;
                *(__half*)(hsn + m16 * 512 + ((jj * 2) ^ ((m16 & 7) << 4))) =
                    __float2half(h);
            }
        }
        __syncthreads();
    }
    // ---- chunk-state writeback
#pragma unroll
    for (int jt = 0; jt < 2; ++jt)
#pragma unroll
        for (int r = 0; r < 4; ++r) {
            int jj = jbase + jt * 16;
            int m16 = mq * 4 + r;
            __half hv = *(const __half*)(hsraw + ((Tc & 1) << 13) + m16 * 512
                                         + ((jj * 2) ^ ((m16 & 7) << 4)));
            h_state[(size_t)(sbase + r) * 256 + jj] = hv;
            c_state[(size_t)(sbase + r) * 256 + jj] = creg[jt][r];
        }
#undef WBASE
#undef LDW
}

// Fallback (ws too small for any xg chunk): fused, streams both fp16 matrices.
__global__ __launch_bounds__(1024) void lstm_fused16(const float* __restrict__ X,
                                                     const __half* __restrict__ Wi16,
                                                     const __half* __restrict__ Wh16,
                                                     const float* __restrict__ bias_p,
                                                     const int* __restrict__ x_len,
                                                     float* __restrict__ out) {
    __shared__ __half hs_h[256];
    __shared__ __half xs_h[256];
    __shared__ float4 part[3][256];
    int tid = threadIdx.x;
    int c = tid & 255, kh = tid >> 8;
    int b = blockIdx.x;
    int len = x_len[b];
    float cst = 0.0f;
    float4 bias;
    if (kh == 0) {
        bias = *(const float4*)&bias_p[4 * c];
        hs_h[c] = __float2half(0.0f);
    }
    const uint4* wph = (const uint4*)(Wh16 + (size_t)(kh * 32) * 2048 + 8 * c);
    const uint4* wpi = (const uint4*)(Wi16 + (size_t)(kh * 32) * 2048 + 8 * c);
    float* outb = out + (size_t)b * 512 * 256 + c;
    __syncthreads();

    for (int t = 0; t < TT; ++t) {
        if (tid < 128) {
            float2 xv = *(const float2*)&X[((size_t)b * 512 + t) * 256 + 2 * tid];
            h2_t xh = {(_Float16)xv.x, (_Float16)xv.y};
            ((h2_t*)xs_h)[tid] = xh;
        }
        __syncthreads();
        float4 acc = {0.0f, 0.0f, 0.0f, 0.0f};
#pragma unroll 4
        for (int i = 0; i < 32; ++i) {
            uint4 uh = wph[(size_t)i * 256];
            uint4 ui = wpi[(size_t)i * 256];
            h2_t hv = ((const h2_t*)hs_h)[kh * 32 + i];
            h2_t xv = ((const h2_t*)xs_h)[kh * 32 + i];
            dot4_(acc, uh, hv);
            dot4_(acc, ui, xv);
        }
        if (kh) part[kh - 1][c] = acc;
        __syncthreads();
        if (kh == 0) {
            float4 p0 = part[0][c], p1 = part[1][c], p2 = part[2][c];
            float gi = acc.x + p0.x + p1.x + p2.x + bias.x;
            float gf = acc.y + p0.y + p1.y + p2.y + bias.y;
            float gg = acc.z + p0.z + p1.z + p2.z + bias.z;
            float go = acc.w + p0.w + p1.w + p2.w + bias.w;
            float iv = sigmoidf_(gi), fv = sigmoidf_(gf);
            float gv = tanhf_(gg),   ov = sigmoidf_(go);
            cst = fv * cst + iv * gv;
            float h = ov * tanhf_(cst);
            outb[(size_t)t * 256] = (t < len) ? h : 0.0f;
            hs_h[c] = __float2half(h);
        }
        __syncthreads();
    }
}

extern "C" void kernel_launch(void* const* d_in, const int* in_sizes, int n_in,
                              void* d_out, int out_size, void* d_ws, size_t ws_size,
                              hipStream_t stream) {
    const float* x     = (const float*)d_in[0];
    const int*   x_len = (const int*)d_in[1];
    const float* W_ih  = (const float*)d_in[2];
    const float* W_hh  = (const float*)d_in[3];
    const float* b_ih  = (const float*)d_in[4];
    const float* b_hh  = (const float*)d_in[5];
    float* out = (float*)d_out;

    char* ws = (char*)d_ws;
    __half* Wh16    = (__half*)(ws);                      // 512 KB (fallback)
    __half* Wi16    = (__half*)(ws + 0x080000);           // 512 KB (fallback)
    __half* Wg16    = (__half*)(ws + 0x100000);           // 512 KB raw W_ih
    __half* Wh16g   = (__half*)(ws + 0x180000);           // 512 KB raw W_hh
    float*  bias_p  = (float*)(ws + 0x200000);            // 4 KB (fallback)
    float*  bias_r  = (float*)(ws + 0x201000);            // 4 KB
    __half* h_state = (__half*)(ws + 0x202000);           // 64 KB
    float*  c_state = (float*)(ws + 0x212000);            // 128 KB
    __half* x16     = (__half*)(ws + 0x232000);           // 33.6 MB
    size_t  o_xg    = 0x232000 + (size_t)0x2000000;
    __half* xg_p    = (__half*)(ws + o_xg);

    int Tc = 0;
    for (int cand = 512; cand >= 16; cand >>= 1)
        if (ws_size >= o_xg + (size_t)cand * 262144) { Tc = cand; break; }

    pack2<<<1024, 256, 0, stream>>>(W_ih, W_hh, b_ih, b_hh,
                                    Wg16, Wh16g, Wi16, Wh16, bias_p, bias_r);
    if (Tc) {
        cvt_x<<<8192, 256, 0, stream>>>(x, x16);
        for (int t0 = 0; t0 < TT; t0 += Tc) {
            dim3 g(2 * Tc, 16);
            xg_gemm2<<<g, 256, 0, stream>>>(x16, Wg16, bias_r, xg_p, t0);
            lstm_mfma16<<<8, 512, 0, stream>>>(xg_p, Wh16g, x_len, out,
                                               h_state, c_state, t0, Tc);
        }
    } else {
        lstm_fused16<<<BB, 1024, 0, stream>>>(x, Wi16, Wh16, bias_p, x_len, out);
    }
}

// Round 6
// 1238.334 us; speedup vs baseline: 3.5107x; 3.5107x over previous
//
#include <hip/hip_runtime.h>
#include <hip/hip_fp16.h>
#include <math.h>

#define BB 128
#define TT 512
#define DD 256
#define HH 256
#define NG 1024  // 4*H

typedef _Float16 h2_t __attribute__((ext_vector_type(2)));
typedef _Float16 f16x8 __attribute__((ext_vector_type(8)));
typedef float f32x4 __attribute__((ext_vector_type(4)));

#if __has_builtin(__builtin_amdgcn_fdot2)
__device__ __forceinline__ float fdot2_(h2_t a, h2_t b, float c) {
    return __builtin_amdgcn_fdot2(a, b, c, false);
}
#else
__device__ __forceinline__ float fdot2_(h2_t a, h2_t b, float c) {
    return c + (float)a.x * (float)b.x + (float)a.y * (float)b.y;
}
#endif

__device__ __forceinline__ float sigmoidf_(float x) {
    return 1.0f / (1.0f + __expf(-x));
}
__device__ __forceinline__ float tanhf_(float x) {
    x = fminf(15.0f, fmaxf(-15.0f, x));
    float e = __expf(2.0f * x);
    return (e - 1.0f) / (e + 1.0f);
}
__device__ __forceinline__ void dot4_(float4& acc, uint4 u, h2_t h) {
    acc.x = fdot2_(__builtin_bit_cast(h2_t, u.x), h, acc.x);
    acc.y = fdot2_(__builtin_bit_cast(h2_t, u.y), h, acc.y);
    acc.z = fdot2_(__builtin_bit_cast(h2_t, u.z), h, acc.z);
    acc.w = fdot2_(__builtin_bit_cast(h2_t, u.w), h, acc.w);
}

// Pair sum across lanes (l, l^1) via DPP quad_perm [1,0,3,2] — VALU pipe,
// no LDS traffic.
#if __has_builtin(__builtin_amdgcn_update_dpp)
__device__ __forceinline__ float pair_sum_(float v) {
    int x = __builtin_bit_cast(int, v);
    int y = __builtin_amdgcn_update_dpp(0, x, 0xB1, 0xF, 0xF, true);
    return v + __builtin_bit_cast(float, y);
}
#else
__device__ __forceinline__ float pair_sum_(float v) {
    return v + __shfl_xor(v, 1, 64);
}
#endif

// Pack: packed col n = j*4+q <-> gate row g = q*256+j  (q: 0=i,1=f,2=g,3=o)
//  Wg16 [n][k] fp16            (MFMA GEMM B operand)
//  Wi16/Wh16 fp16 k-pair-major (halfs at ((k>>1)*1024 + n)*2 + (k&1))
//  bias_p[n] = b_ih[g] + b_hh[g]
__global__ void pack2(const float* __restrict__ W_ih, const float* __restrict__ W_hh,
                      const float* __restrict__ b_ih, const float* __restrict__ b_hh,
                      __half* __restrict__ Wg16, __half* __restrict__ Wi16,
                      __half* __restrict__ Wh16, float* __restrict__ bias_p) {
    int idx = blockIdx.x * 256 + threadIdx.x;   // 0..262143
    int n = idx >> 8;
    int k = idx & 255;
    int g = (n & 3) * 256 + (n >> 2);
    float wih = W_ih[g * 256 + k];
    float whh = W_hh[g * 256 + k];
    Wg16[n * 256 + k] = __float2half(wih);
    size_t hidx = ((size_t)(k >> 1) * 1024 + n) * 2 + (k & 1);
    Wi16[hidx] = __float2half(wih);
    Wh16[hidx] = __float2half(whh);
    if (idx < 1024) {
        int gg = (idx & 3) * 256 + (idx >> 2);
        bias_p[idx] = b_ih[gg] + b_hh[gg];
    }
}

// x fp32 -> fp16, 8 elements/thread
__global__ __launch_bounds__(256) void cvt_x(const float* __restrict__ X,
                                             __half* __restrict__ X16) {
    size_t i = ((size_t)blockIdx.x * 256 + threadIdx.x) * 8;
    float4 a = *(const float4*)&X[i];
    float4 b = *(const float4*)&X[i + 4];
    f16x8 v;
    v[0] = (_Float16)a.x; v[1] = (_Float16)a.y; v[2] = (_Float16)a.z; v[3] = (_Float16)a.w;
    v[4] = (_Float16)b.x; v[5] = (_Float16)b.y; v[6] = (_Float16)b.z; v[7] = (_Float16)b.w;
    *(f16x8*)&X16[i] = v;
}

// xg chunk GEMM via MFMA f16: M = 128*Tc, N = 1024, K = 256.
__global__ __launch_bounds__(256) void xg_gemm_mfma(const __half* __restrict__ X16,
                                                    const __half* __restrict__ Wg16,
                                                    const float* __restrict__ bias_p,
                                                    __half* __restrict__ xg,
                                                    int t0, int lTc, int tcMask) {
    __shared__ __align__(16) __half st[4][16][72];
    int tid = threadIdx.x;
    int w = tid >> 6, lane = tid & 63;
    int row16 = lane & 15, quad = lane >> 4;
    int m0 = blockIdx.x * 64 + w * 16;
    int n0 = blockIdx.y * 64;

    int mrow = m0 + row16;                                   // chunk-local row
    size_t xrow = (size_t)(mrow >> lTc) * 512 + t0 + (mrow & tcMask);
    const __half* aptr = X16 + xrow * 256 + quad * 8;
    f16x8 afrag[8];
#pragma unroll
    for (int kk = 0; kk < 8; ++kk)
        afrag[kk] = *(const f16x8*)(aptr + kk * 32);

#pragma unroll
    for (int cg = 0; cg < 4; ++cg) {
        int n = n0 + cg * 16 + row16;
        const __half* bptr = Wg16 + (size_t)n * 256 + quad * 8;
        f32x4 acc = {0.0f, 0.0f, 0.0f, 0.0f};
#pragma unroll
        for (int kk = 0; kk < 8; ++kk) {
            f16x8 bfrag = *(const f16x8*)(bptr + kk * 32);
            acc = __builtin_amdgcn_mfma_f32_16x16x32_f16(afrag[kk], bfrag, acc, 0, 0, 0);
        }
        float bias = bias_p[n];
#pragma unroll
        for (int r = 0; r < 4; ++r)
            st[w][quad * 4 + r][cg * 16 + row16] = __float2half(acc[r] + bias);
    }
    __syncthreads();
    int ml = lane >> 2, cq = lane & 3;
    int mout = blockIdx.x * 64 + w * 16 + ml;                // chunk-local row
    const uint4* src = (const uint4*)&st[w][ml][cq * 16];
    uint4 v0 = src[0], v1 = src[1];
    *(uint4*)&xg[(size_t)mout * 1024 + n0 + cq * 16] = v0;
    *(uint4*)&xg[(size_t)mout * 1024 + n0 + cq * 16 + 8] = v1;
}

// Recurrence v7: the R1 structure (measured-best: rec 901 us) + the two
// conflict fixes verified in R2/R3, nothing else:
//   - wreg[44] UNPINNED: the allocator remats ~half into per-step L1/L2
//     loads (VGPR_Count ~120). R2 ("+v" pin) and R3 (volatile accvgpr)
//     both regressed vs this behavior — leave the allocator alone.
//   - lw layout [i][c][kh] (element = i*512 + tid): wave reads 64
//     consecutive uint4 per ds_read_b128 -> conflict-free (R2-verified).
//     Grown 16 -> 19 k-pairs (152 KB, size verified R3/R5): explicit
//     streaming shrinks 4 -> 1 k-pair.
//   - hs padded [2][272] with kh=1 half at uint4 18: the two broadcast
//     addresses per wave-read land in different bank slots (R3-verified:
//     conflicts -> 0).
// Thread (c = tid>>1, kh = tid&1): 4 gates of col c, k-half kh (64 k-pairs).
// Residency: k-pairs 0..43 wreg/remat, 44..62 LDS, 63 streamed explicitly.
__global__ __launch_bounds__(512, 2) void lstm_rec4(const __half* __restrict__ xg,
                                                    const __half* __restrict__ Wh16,
                                                    const int* __restrict__ x_len,
                                                    float* __restrict__ out,
                                                    __half* __restrict__ h_state,
                                                    float* __restrict__ c_state,
                                                    int t0, int Tc) {
    __shared__ __align__(16) uint4 lw[9728];        // [i<19][c<256][kh<2] : 152 KB
    __shared__ __align__(16) __half hs[2][272];     // padded double-buffered h
    int tid = threadIdx.x;
    int c = tid >> 1, kh = tid & 1;
    int b = blockIdx.x;
    int len = x_len[b];
    const uint4* W4 = (const uint4*)Wh16;           // index: p*256 + c  (p = k-pair)

    // LDS fill: element j = i*512 + c2*2 + kh2 <- k-pair (kh2*64 + 44 + i), col c2
    for (int j = tid; j < 9728; j += 512) {
        int i2 = j >> 9, c2 = (j >> 1) & 255, kh2 = j & 1;
        lw[j] = W4[(size_t)(kh2 * 64 + 44 + i2) * 256 + c2];
    }
    // Register-resident weights (allocator-managed): k-pairs kh*64 + 0..43
    const uint4* wp = W4 + (size_t)(kh * 64) * 256 + c;
    uint4 wreg[44];
#pragma unroll
    for (int i = 0; i < 44; ++i) wreg[i] = wp[(size_t)i * 256];

    float cst = 0.0f;
    float hlast = 0.0f;
    if (t0 != 0) cst = c_state[b * 256 + c];        // replicated in both lanes
    if (kh == 0)
        hs[0][c + ((c >> 7) << 4)] = (t0 == 0) ? __float2half(0.0f)
                                               : h_state[b * 256 + c];

    const __half* xgb = xg + (size_t)b * Tc * 1024 + 4 * c;
    float* outb = out + ((size_t)b * 512 + t0) * 256 + c;
    const uint4* lwb = lw + tid;                    // [i*512] strides
    __syncthreads();

    for (int tt = 0; tt < Tc; ++tt) {
        // streamed weight + xg first (in flight during resident dot2s)
        uint4 s0 = wp[(size_t)63 * 256];
        uint2 xr = *(const uint2*)(xgb + (size_t)tt * 1024);

        // kh-half base: kh=0 -> uint4 idx 0, kh=1 -> idx 18 (byte 288)
        const uint4* h4 = (const uint4*)(hs[tt & 1]) + kh * 18;
        float4 acc = {0.0f, 0.0f, 0.0f, 0.0f};
        // j = 0..10: k-pairs 0..43 in wreg (allocator: regs or remat loads)
#pragma unroll
        for (int j = 0; j < 11; ++j) {
            uint4 hv = h4[j];
            dot4_(acc, wreg[j * 4 + 0], __builtin_bit_cast(h2_t, hv.x));
            dot4_(acc, wreg[j * 4 + 1], __builtin_bit_cast(h2_t, hv.y));
            dot4_(acc, wreg[j * 4 + 2], __builtin_bit_cast(h2_t, hv.z));
            dot4_(acc, wreg[j * 4 + 3], __builtin_bit_cast(h2_t, hv.w));
        }
        // j = 11..14: k-pairs 44..59 from LDS (i = 0..15)
#pragma unroll
        for (int j = 11; j < 15; ++j) {
            uint4 hv = h4[j];
            int i0 = (j - 11) * 4;
            dot4_(acc, lwb[(i0 + 0) * 512], __builtin_bit_cast(h2_t, hv.x));
            dot4_(acc, lwb[(i0 + 1) * 512], __builtin_bit_cast(h2_t, hv.y));
            dot4_(acc, lwb[(i0 + 2) * 512], __builtin_bit_cast(h2_t, hv.z));
            dot4_(acc, lwb[(i0 + 3) * 512], __builtin_bit_cast(h2_t, hv.w));
        }
        // j = 15: k-pairs 60,61,62 LDS (i = 16,17,18) + 63 streamed
        {
            uint4 hv = h4[15];
            dot4_(acc, lwb[16 * 512], __builtin_bit_cast(h2_t, hv.x));
            dot4_(acc, lwb[17 * 512], __builtin_bit_cast(h2_t, hv.y));
            dot4_(acc, lwb[18 * 512], __builtin_bit_cast(h2_t, hv.z));
            dot4_(acc, s0, __builtin_bit_cast(h2_t, hv.w));
        }
        // reduce partials over kh (lanes l, l^1) on the VALU pipe
        float gi = pair_sum_(acc.x);
        float gf = pair_sum_(acc.y);
        float gg = pair_sum_(acc.z);
        float go = pair_sum_(acc.w);
        h2_t x01 = __builtin_bit_cast(h2_t, xr.x);
        h2_t x23 = __builtin_bit_cast(h2_t, xr.y);
        gi += (float)x01.x;
        gf += (float)x01.y;
        gg += (float)x23.x;
        go += (float)x23.y;
        // gate math: both lanes redundantly (identical inputs -> identical cst)
        float iv = sigmoidf_(gi), fv = sigmoidf_(gf);
        float gv = tanhf_(gg),   ov = sigmoidf_(go);
        cst = fv * cst + iv * gv;
        float h = ov * tanhf_(cst);
        hlast = h;
        if (kh == 0) {
            outb[(size_t)tt * 256] = (t0 + tt < len) ? h : 0.0f;
            hs[(tt & 1) ^ 1][c + ((c >> 7) << 4)] = __float2half(h);
        }
        __syncthreads();
    }
    if (kh == 0) {
        h_state[b * 256 + c] = __float2half(hlast);
        c_state[b * 256 + c] = cst;
    }
}

// Fallback (ws too small for any xg chunk): fused, streams both fp16 matrices.
__global__ __launch_bounds__(1024) void lstm_fused16(const float* __restrict__ X,
                                                     const __half* __restrict__ Wi16,
                                                     const __half* __restrict__ Wh16,
                                                     const float* __restrict__ bias_p,
                                                     const int* __restrict__ x_len,
                                                     float* __restrict__ out) {
    __shared__ __half hs_h[256];
    __shared__ __half xs_h[256];
    __shared__ float4 part[3][256];
    int tid = threadIdx.x;
    int c = tid & 255, kh = tid >> 8;
    int b = blockIdx.x;
    int len = x_len[b];
    float cst = 0.0f;
    float4 bias;
    if (kh == 0) {
        bias = *(const float4*)&bias_p[4 * c];
        hs_h[c] = __float2half(0.0f);
    }
    const uint4* wph = (const uint4*)(Wh16 + (size_t)(kh * 32) * 2048 + 8 * c);
    const uint4* wpi = (const uint4*)(Wi16 + (size_t)(kh * 32) * 2048 + 8 * c);
    float* outb = out + (size_t)b * 512 * 256 + c;
    __syncthreads();

    for (int t = 0; t < TT; ++t) {
        if (tid < 128) {
            float2 xv = *(const float2*)&X[((size_t)b * 512 + t) * 256 + 2 * tid];
            h2_t xh = {(_Float16)xv.x, (_Float16)xv.y};
            ((h2_t*)xs_h)[tid] = xh;
        }
        __syncthreads();
        float4 acc = {0.0f, 0.0f, 0.0f, 0.0f};
#pragma unroll 4
        for (int i = 0; i < 32; ++i) {
            uint4 uh = wph[(size_t)i * 256];
            uint4 ui = wpi[(size_t)i * 256];
            h2_t hv = ((const h2_t*)hs_h)[kh * 32 + i];
            h2_t xv = ((const h2_t*)xs_h)[kh * 32 + i];
            dot4_(acc, uh, hv);
            dot4_(acc, ui, xv);
        }
        if (kh) part[kh - 1][c] = acc;
        __syncthreads();
        if (kh == 0) {
            float4 p0 = part[0][c], p1 = part[1][c], p2 = part[2][c];
            float gi = acc.x + p0.x + p1.x + p2.x + bias.x;
            float gf = acc.y + p0.y + p1.y + p2.y + bias.y;
            float gg = acc.z + p0.z + p1.z + p2.z + bias.z;
            float go = acc.w + p0.w + p1.w + p2.w + bias.w;
            float iv = sigmoidf_(gi), fv = sigmoidf_(gf);
            float gv = tanhf_(gg),   ov = sigmoidf_(go);
            cst = fv * cst + iv * gv;
            float h = ov * tanhf_(cst);
            outb[(size_t)t * 256] = (t < len) ? h : 0.0f;
            hs_h[c] = __float2half(h);
        }
        __syncthreads();
    }
}

extern "C" void kernel_launch(void* const* d_in, const int* in_sizes, int n_in,
                              void* d_out, int out_size, void* d_ws, size_t ws_size,
                              hipStream_t stream) {
    const float* x     = (const float*)d_in[0];
    const int*   x_len = (const int*)d_in[1];
    const float* W_ih  = (const float*)d_in[2];
    const float* W_hh  = (const float*)d_in[3];
    const float* b_ih  = (const float*)d_in[4];
    const float* b_hh  = (const float*)d_in[5];
    float* out = (float*)d_out;

    char* ws = (char*)d_ws;
    __half* Wh16    = (__half*)(ws);                      // 512 KB
    __half* Wi16    = (__half*)(ws + 0x080000);           // 512 KB
    __half* Wg16    = (__half*)(ws + 0x100000);           // 512 KB
    float*  bias_p  = (float*)(ws + 0x180000);            // 4 KB
    __half* h_state = (__half*)(ws + 0x181000);           // 64 KB
    float*  c_state = (float*)(ws + 0x191000);            // 128 KB
    __half* x16     = (__half*)(ws + 0x1B1000);           // 33.6 MB
    size_t  o_xg    = 0x1B1000 + (size_t)0x2004000;
    __half* xg      = (__half*)(ws + o_xg);

    int Tc = 0;
    for (int cand = 512; cand >= 16; cand >>= 1)
        if (ws_size >= o_xg + (size_t)cand * 262144) { Tc = cand; break; }

    pack2<<<1024, 256, 0, stream>>>(W_ih, W_hh, b_ih, b_hh,
                                    Wg16, Wi16, Wh16, bias_p);
    if (Tc) {
        cvt_x<<<8192, 256, 0, stream>>>(x, x16);
        int lTc = 31 - __builtin_clz((unsigned)Tc);
        for (int t0 = 0; t0 < TT; t0 += Tc) {
            dim3 g(2 * Tc, 16);   // (128*Tc/64, 1024/64)
            xg_gemm_mfma<<<g, 256, 0, stream>>>(x16, Wg16, bias_p, xg,
                                                t0, lTc, Tc - 1);
            lstm_rec4<<<BB, 512, 0, stream>>>(xg, Wh16, x_len, out,
                                              h_state, c_state, t0, Tc);
        }
    } else {
        lstm_fused16<<<BB, 1024, 0, stream>>>(x, Wi16, Wh16, bias_p, x_len, out);
    }
}